// Round 11
// baseline (247.320 us; speedup 1.0000x reference)
//
#include <hip/hip_runtime.h>
#include <hip/hip_bf16.h>

// Problem dims (fixed): B=4, N=256, D=512, L=3
#define BB 4
#define NN 256
#define DD 512

using short8   = __attribute__((ext_vector_type(8))) short;
using f32x4    = __attribute__((ext_vector_type(4))) float;
using uint32x4 = __attribute__((ext_vector_type(4))) unsigned int;

__device__ __forceinline__ unsigned short f2bf(float f) {
    unsigned int u = __float_as_uint(f);
    unsigned int r = (u + 0x7fffu + ((u >> 16) & 1u)) >> 16;
    return (unsigned short)r;
}

// packed f32->bf16 (RNE), 2 elems/instr
__device__ __forceinline__ unsigned cvtpk(float lo, float hi) {
    unsigned r;
    asm("v_cvt_pk_bf16_f32 %0, %1, %2" : "=v"(r) : "v"(lo), "v"(hi));
    return r;
}

// Stage a ROWSx64 bf16 tile from row-major global (stride elems) into LDS,
// XOR-swizzled: LDS slot s of row r holds global 16B-slot (s ^ (r&7)).
template <int ROWS, int NW>
__device__ __forceinline__ void stage_rows(const unsigned short* src, int stride,
                                           short* dst, int tid) {
    int wave = tid >> 6, lane = tid & 63;
#pragma unroll
    for (int c = 0; c < ROWS / (8 * NW); ++c) {
        int rbase = (c * NW + wave) * 8;
        int row   = rbase + (lane >> 3);
        int slot  = (lane & 7) ^ (row & 7);
        const unsigned short* g = src + (size_t)row * stride + slot * 8;
        __builtin_amdgcn_global_load_lds(
            (const __attribute__((address_space(1))) void*)g,
            (__attribute__((address_space(3))) void*)(dst + rbase * 64),
            16, 0, 0);
    }
}

// Read an MFMA A/B fragment (16 rows x 32 k) from a swizzled [ROWS][64] bf16 tile.
__device__ __forceinline__ short8 read_frag(const short* T, int rowBase, int k2) {
    int lane = threadIdx.x & 63;
    int row  = rowBase + (lane & 15);
    int slot = ((k2 * 4) + (lane >> 4)) ^ (row & 7);
    return *(const short8*)(T + row * 64 + slot * 8);
}

// ---------------- prep: fp32 -> bf16 weight conversion + h0 init ----------------
__global__ void prep_kernel(const float* __restrict__ x,
                            const float* __restrict__ gw, const float* __restrict__ tw,
                            const float* __restrict__ w0, const float* __restrict__ w1,
                            float* __restrict__ h0_f32, unsigned short* __restrict__ h0_bf,
                            unsigned short* __restrict__ wg_bf, unsigned short* __restrict__ wt_bf,
                            unsigned short* __restrict__ w0c_bf, unsigned short* __restrict__ w1_bf) {
    const int S_X = BB * NN * DD;
    const int S_W = 3 * DD * DD;
    const int S_W0 = 2 * DD * DD;
    int total = S_X + S_W + S_W + S_W0 + DD * DD;
    for (int idx = blockIdx.x * blockDim.x + threadIdx.x; idx < total;
         idx += gridDim.x * blockDim.x) {
        int t = idx;
        if (t < S_X) { float v = x[t]; h0_f32[t] = v; h0_bf[t] = f2bf(v); continue; }
        t -= S_X;
        if (t < S_W) { wg_bf[t] = f2bf(gw[t]); continue; }
        t -= S_W;
        if (t < S_W) { wt_bf[t] = f2bf(tw[t]); continue; }
        t -= S_W;
        if (t < S_W0) {
            int e = t >> 9, d = t & 511;
            float v = (e < DD) ? w0[e * (2 * DD) + d] : w0[(e - DD) * (2 * DD) + DD + d];
            w0c_bf[t] = f2bf(v); continue;
        }
        t -= S_W0;
        w1_bf[t] = f2bf(w1[t]);
    }
}

// ---------------- highway layer (64x64 tiles, 4 waves, 128 blocks) ----------------
__global__ __launch_bounds__(256) void highway_kernel(
        const float* __restrict__ h_in, const unsigned short* __restrict__ hbf_in,
        const unsigned short* __restrict__ wg_bf, const unsigned short* __restrict__ wt_bf,
        const float* __restrict__ gb, const float* __restrict__ tb,
        float* __restrict__ h_out, unsigned short* __restrict__ hbf_out) {
    __shared__ short ht[64 * 64];
    __shared__ short wgt[64 * 64];
    __shared__ short wtt[64 * 64];
    int tid = threadIdx.x, lane = tid & 63, wave = tid >> 6;
    int mt = blockIdx.x >> 3, et = blockIdx.x & 7;
    int m0 = mt * 64, e0 = et * 64;
    int wm = wave >> 1, we = wave & 1;
    f32x4 gacc[2][2] = {}, tacc[2][2] = {};
    for (int ks = 0; ks < 8; ++ks) {
        int d0 = ks * 64;
        __syncthreads();
        stage_rows<64, 4>(hbf_in + (size_t)m0 * DD + d0, DD, ht, tid);
        stage_rows<64, 4>(wg_bf + (size_t)e0 * DD + d0, DD, wgt, tid);
        stage_rows<64, 4>(wt_bf + (size_t)e0 * DD + d0, DD, wtt, tid);
        __syncthreads();
#pragma unroll
        for (int k2 = 0; k2 < 2; ++k2) {
            short8 af[2], bg[2], bt[2];
#pragma unroll
            for (int f = 0; f < 2; ++f) af[f] = read_frag(ht, wm * 32 + f * 16, k2);
#pragma unroll
            for (int f = 0; f < 2; ++f) bg[f] = read_frag(wgt, we * 32 + f * 16, k2);
#pragma unroll
            for (int f = 0; f < 2; ++f) bt[f] = read_frag(wtt, we * 32 + f * 16, k2);
#pragma unroll
            for (int fm = 0; fm < 2; ++fm)
#pragma unroll
                for (int fn = 0; fn < 2; ++fn) {
                    gacc[fm][fn] = __builtin_amdgcn_mfma_f32_16x16x32_bf16(af[fm], bg[fn], gacc[fm][fn], 0, 0, 0);
                    tacc[fm][fn] = __builtin_amdgcn_mfma_f32_16x16x32_bf16(af[fm], bt[fn], tacc[fm][fn], 0, 0, 0);
                }
        }
    }
#pragma unroll
    for (int fm = 0; fm < 2; ++fm)
#pragma unroll
        for (int fn = 0; fn < 2; ++fn) {
            int e = e0 + we * 32 + fn * 16 + (lane & 15);
            float gbe = gb[e], tbe = tb[e];
#pragma unroll
            for (int r = 0; r < 4; ++r) {
                int m = m0 + wm * 32 + fm * 16 + (lane >> 4) * 4 + r;
                float g = 1.f / (1.f + __expf(-(gacc[fm][fn][r] + gbe)));
                float tv = tacc[fm][fn][r] + tbe; tv = tv > 0.f ? tv : 0.f;
                float ho = h_in[(size_t)m * DD + e];
                float hn = g * tv + (1.f - g) * ho;
                h_out[(size_t)m * DD + e] = hn;
                hbf_out[(size_t)m * DD + e] = f2bf(hn);
            }
        }
}

// ---------------- a/b projection (64x128 tiles, 4 waves, 128 blocks) ------------
__global__ __launch_bounds__(256) void ab_kernel(
        const unsigned short* __restrict__ hbf, const unsigned short* __restrict__ w0c_bf,
        const float* __restrict__ lw0_b,
        float* __restrict__ a_out, float* __restrict__ b_out) {
    __shared__ short ht[64 * 64];
    __shared__ short wt_[128 * 64];
    int tid = threadIdx.x, lane = tid & 63, wave = tid >> 6;
    int mt = blockIdx.x >> 3, et = blockIdx.x & 7;
    int m0 = mt * 64, e0 = et * 128;
    int wm = wave >> 1, we = wave & 1;
    f32x4 acc[2][4] = {};
    for (int ks = 0; ks < 8; ++ks) {
        __syncthreads();
        stage_rows<64, 4>(hbf + (size_t)m0 * DD + ks * 64, DD, ht, tid);
        stage_rows<128, 4>(w0c_bf + (size_t)e0 * DD + ks * 64, DD, wt_, tid);
        __syncthreads();
#pragma unroll
        for (int k2 = 0; k2 < 2; ++k2) {
            short8 af[2], bf_[4];
#pragma unroll
            for (int f = 0; f < 2; ++f) af[f] = read_frag(ht, wm * 32 + f * 16, k2);
#pragma unroll
            for (int f = 0; f < 4; ++f) bf_[f] = read_frag(wt_, we * 64 + f * 16, k2);
#pragma unroll
            for (int fm = 0; fm < 2; ++fm)
#pragma unroll
                for (int fn = 0; fn < 4; ++fn)
                    acc[fm][fn] = __builtin_amdgcn_mfma_f32_16x16x32_bf16(af[fm], bf_[fn], acc[fm][fn], 0, 0, 0);
        }
    }
#pragma unroll
    for (int fm = 0; fm < 2; ++fm)
#pragma unroll
        for (int fn = 0; fn < 4; ++fn) {
            int e = e0 + we * 64 + fn * 16 + (lane & 15);
#pragma unroll
            for (int r = 0; r < 4; ++r) {
                int m = m0 + wm * 32 + fm * 16 + (lane >> 4) * 4 + r;
                float v = acc[fm][fn][r];
                if (e < DD) a_out[(size_t)m * DD + e] = v + lw0_b[e];
                else        b_out[(size_t)m * DD + (e - DD)] = v;
            }
        }
}

// -------- fused pairwise kernel (v11: e-split, 32-reg acc, 2 blocks/CU) --------
// Grid 8192 = 2048 (b,i,j0) x 4 e-quarters. Block: 128j x 128e, 512 threads,
// 8 waves = 4 j-groups x 2 e-groups; wave = 32j x 64e -> acc[2][4] = 32 regs.
// Total wave state ~113 regs -> 4 waves/SIMD; LDS 64KB -> 2 blocks/CU. The two
// resident blocks have independent barriers: one block's stage/drain overlaps
// the other's MFMA (TLP replaces intra-block pipelining). W1 [128e][64k] 2x16KB
// dbuf, z [128j][64k] 2x16KB dbuf, v10's safe drain discipline. Block writes
// 128-e partial logits (no bias/sigmoid); combine_kernel finishes.

#define Z_LOADS(K)                                                            \
    {                                                                         \
        const int dl_ = (K) * 64 + s * 8;                                     \
        alo = *(const f32x4*)(arow + dl_);                                    \
        ahi = *(const f32x4*)(arow + dl_ + 4);                                \
        const float* b0_ = brow + (size_t)rr * DD + dl_;                      \
        const float* b1_ = brow + (size_t)(64 + rr) * DD + dl_;               \
        b0lo = *(const f32x4*)b0_; b0hi = *(const f32x4*)(b0_ + 4);           \
        b1lo = *(const f32x4*)b1_; b1hi = *(const f32x4*)(b1_ + 4);           \
    }

#define Z_MATH()                                                              \
    {                                                                         \
        zw0[0] = cvtpk(fmaxf(alo[0] + b0lo[0], 0.f), fmaxf(alo[1] + b0lo[1], 0.f)); \
        zw0[1] = cvtpk(fmaxf(alo[2] + b0lo[2], 0.f), fmaxf(alo[3] + b0lo[3], 0.f)); \
        zw0[2] = cvtpk(fmaxf(ahi[0] + b0hi[0], 0.f), fmaxf(ahi[1] + b0hi[1], 0.f)); \
        zw0[3] = cvtpk(fmaxf(ahi[2] + b0hi[2], 0.f), fmaxf(ahi[3] + b0hi[3], 0.f)); \
        zw1[0] = cvtpk(fmaxf(alo[0] + b1lo[0], 0.f), fmaxf(alo[1] + b1lo[1], 0.f)); \
        zw1[1] = cvtpk(fmaxf(alo[2] + b1lo[2], 0.f), fmaxf(alo[3] + b1lo[3], 0.f)); \
        zw1[2] = cvtpk(fmaxf(ahi[0] + b1hi[0], 0.f), fmaxf(ahi[1] + b1hi[1], 0.f)); \
        zw1[3] = cvtpk(fmaxf(ahi[2] + b1hi[2], 0.f), fmaxf(ahi[3] + b1hi[3], 0.f)); \
    }

#define Z_WRITE(BUF)                                                          \
    {                                                                         \
        *(uint32x4*)((BUF) + rr * 64 + ((s ^ (rr & 7)) * 8)) = zw0;           \
        const int r1_ = 64 + rr;                                              \
        *(uint32x4*)((BUF) + r1_ * 64 + ((s ^ (r1_ & 7)) * 8)) = zw1;         \
    }

__global__ __launch_bounds__(512, 4) void pair_kernel(
        const float* __restrict__ a_f32, const float* __restrict__ b_f32,
        const unsigned short* __restrict__ w1_bf,
        const float* __restrict__ lw1_b, const float* __restrict__ lwo_w,
        float* __restrict__ part) {
    __shared__ short ws[2][128 * 64];    // 32KB W1 double buffer (128 e-rows)
    __shared__ short zs[2][128 * 64];    // 32KB z double buffer; s_red alias after
    int tid = threadIdx.x, lane = tid & 63, wave = tid >> 6;
    int bid = blockIdx.x;
    int eq = bid >> 11;                  // e-quarter 0..3
    int ij = bid & 2047;
    // bijective XCD swizzle on ij: each XCD's blocks cover a contiguous i-range
    int swz = (ij & 7) * 256 + (ij >> 3);
    int bb = swz >> 9, i = (swz >> 1) & 255, j0 = (swz & 1) * 128;
    int e0 = eq * 128;
    const float* arow = a_f32 + (size_t)(bb * NN + i) * DD;
    const float* brow = b_f32 + (size_t)(bb * NN + j0) * DD;
    int s = tid & 7, rr = tid >> 3;      // z producer coords (rr: 0..63)
    int jg = wave >> 1, eg = wave & 1;   // j-group (32 j), e-group (64 e)

    f32x4 acc[2][4] = {};
    uint32x4 zw0, zw1;
    f32x4 alo, ahi, b0lo, b0hi, b1lo, b1hi;

    // ---- prologue ----
    Z_LOADS(0)
    __builtin_amdgcn_sched_barrier(0);
    stage_rows<128, 8>(w1_bf + (size_t)e0 * DD, DD, ws[0], tid);
    __builtin_amdgcn_sched_barrier(0);
    Z_MATH()                             // implicit vmcnt(2): stage(0) in flight
    Z_WRITE(zs[0])
    asm volatile("s_waitcnt lgkmcnt(0)" ::: "memory");
    __builtin_amdgcn_s_barrier();        // zs[0] visible
    asm volatile("s_waitcnt vmcnt(0)" ::: "memory");   // own stage(0) landed
    __builtin_amdgcn_s_barrier();        // all waves' stage(0) landed

#pragma unroll
    for (int k = 0; k < 8; ++k) {
        const short* zc = zs[k & 1];
        const short* wc = ws[k & 1];

        // ---- issue phase: a/b first, then W1 stage (order pinned) ----
        if (k < 7) {
            Z_LOADS(k + 1)
            __builtin_amdgcn_sched_barrier(0);
            stage_rows<128, 8>(w1_bf + (size_t)e0 * DD + (k + 1) * 64, DD,
                               ws[(k + 1) & 1], tid);
            __builtin_amdgcn_sched_barrier(0);
        }

        // ---- MFMA phase: 16 MFMA, 12 ds_reads ----
#pragma unroll
        for (int k2 = 0; k2 < 2; ++k2) {
            short8 af[2], bfr[4];
#pragma unroll
            for (int f = 0; f < 4; ++f) bfr[f] = read_frag(wc, eg * 64 + f * 16, k2);
#pragma unroll
            for (int f = 0; f < 2; ++f) af[f] = read_frag(zc, jg * 32 + f * 16, k2);
            __builtin_amdgcn_s_setprio(1);
#pragma unroll
            for (int fm = 0; fm < 2; ++fm)
#pragma unroll
                for (int fn = 0; fn < 4; ++fn)
                    acc[fm][fn] = __builtin_amdgcn_mfma_f32_16x16x32_bf16(
                        af[fm], bfr[fn], acc[fm][fn], 0, 0, 0);
            __builtin_amdgcn_s_setprio(0);
        }

        // ---- z(k+1): math (waits only a/b) + swizzled write ----
        if (k < 7) {
            Z_MATH()
            Z_WRITE(zs[(k + 1) & 1])
            asm volatile("s_waitcnt lgkmcnt(0)" ::: "memory");
        }
        __builtin_amdgcn_s_barrier();    // zs[(k+1)&1] visible
        if (k < 7) {
            asm volatile("s_waitcnt vmcnt(0)" ::: "memory"); // own stage: ~1 step old
            __builtin_amdgcn_s_barrier();                    // all DMA landed
        }
    }

    // ---- epilogue: relu(acc+b1)*wo partial over this block's 128 e ----
    __syncthreads();                     // zs reads done -> alias as s_red
    float* s_red = (float*)zs;           // 2 eg x 128 j partials
#pragma unroll
    for (int fm = 0; fm < 2; ++fm) {
        float red[4] = {0.f, 0.f, 0.f, 0.f};
#pragma unroll
        for (int fn = 0; fn < 4; ++fn) {
            int e = e0 + eg * 64 + fn * 16 + (lane & 15);
            float b1e = lw1_b[e], woe = lwo_w[e];
#pragma unroll
            for (int r = 0; r < 4; ++r) {
                float v = acc[fm][fn][r] + b1e;
                red[r] += (v > 0.f) ? v * woe : 0.f;
            }
        }
#pragma unroll
        for (int mask = 1; mask < 16; mask <<= 1)
#pragma unroll
            for (int r = 0; r < 4; ++r) red[r] += __shfl_xor(red[r], mask, 64);
        if ((lane & 15) == 0) {
#pragma unroll
            for (int r = 0; r < 4; ++r)
                s_red[eg * 128 + jg * 32 + fm * 16 + (lane >> 4) * 4 + r] = red[r];
        }
    }
    __syncthreads();
    if (tid < 128) {
        float v = s_red[tid] + s_red[128 + tid];
        part[(size_t)eq * (BB * NN * NN) + ((size_t)(bb * NN + i)) * NN + j0 + tid] = v;
    }
}

// ---------------- combine: out = sigmoid(sum_eq part + bo) ----------------
__global__ __launch_bounds__(256) void combine_kernel(
        const float* __restrict__ part, const float* __restrict__ lwo_b,
        float* __restrict__ out) {
    const int T = BB * NN * NN;          // 262144
    int idx = blockIdx.x * 256 + threadIdx.x;
    if (idx < T) {
        float v = part[idx] + part[T + idx] + part[2 * T + idx] +
                  part[3 * T + idx] + lwo_b[0];
        out[idx] = 1.f / (1.f + __expf(-v));
    }
}

extern "C" void kernel_launch(void* const* d_in, const int* in_sizes, int n_in,
                              void* d_out, int out_size, void* d_ws, size_t ws_size,
                              hipStream_t stream) {
    const float* x    = (const float*)d_in[0];
    const float* gw   = (const float*)d_in[1];
    const float* gb   = (const float*)d_in[2];
    const float* tw   = (const float*)d_in[3];
    const float* tb   = (const float*)d_in[4];
    const float* w0   = (const float*)d_in[5];
    const float* w0b  = (const float*)d_in[6];
    const float* w1   = (const float*)d_in[7];
    const float* w1b_ = (const float*)d_in[8];
    const float* wo   = (const float*)d_in[9];
    const float* wob  = (const float*)d_in[10];
    float* out = (float*)d_out;

    char* w = (char*)d_ws;
    float* hA  = (float*)w;            w += (size_t)BB * NN * DD * 4;   // 2MB \ after ab_kernel these 6MB are
    float* hB  = (float*)w;            w += (size_t)BB * NN * DD * 4;   // 2MB | dead -> reused as the 4MB
    unsigned short* hbA = (unsigned short*)w; w += (size_t)BB * NN * DD * 2; // | partial-logit buffer
    unsigned short* hbB = (unsigned short*)w; w += (size_t)BB * NN * DD * 2; // /
    float* a_f = (float*)w;            w += (size_t)BB * NN * DD * 4;
    float* b_f = (float*)w;            w += (size_t)BB * NN * DD * 4;
    unsigned short* wg_bf  = (unsigned short*)w; w += (size_t)3 * DD * DD * 2;
    unsigned short* wt_bf  = (unsigned short*)w; w += (size_t)3 * DD * DD * 2;
    unsigned short* w0c_bf = (unsigned short*)w; w += (size_t)2 * DD * DD * 2;
    unsigned short* w1_bf  = (unsigned short*)w; w += (size_t)DD * DD * 2;

    float* part = hA;   // 4MB: 4 e-quarters x [B,N,N] f32 (aliases hA+hB, dead by then)

    prep_kernel<<<1024, 256, 0, stream>>>(x, gw, tw, w0, w1, hA, hbA, wg_bf, wt_bf, w0c_bf, w1_bf);

    highway_kernel<<<128, 256, 0, stream>>>(hA, hbA, wg_bf + 0 * DD * DD, wt_bf + 0 * DD * DD,
                                            gb + 0 * DD, tb + 0 * DD, hB, hbB);
    highway_kernel<<<128, 256, 0, stream>>>(hB, hbB, wg_bf + 1 * DD * DD, wt_bf + 1 * DD * DD,
                                            gb + 1 * DD, tb + 1 * DD, hA, hbA);
    highway_kernel<<<128, 256, 0, stream>>>(hA, hbA, wg_bf + 2 * DD * DD, wt_bf + 2 * DD * DD,
                                            gb + 2 * DD, tb + 2 * DD, hB, hbB);

    ab_kernel<<<128, 256, 0, stream>>>(hbB, w0c_bf, w0b, a_f, b_f);

    pair_kernel<<<8192, 512, 0, stream>>>(a_f, b_f, w1_bf, w1b_, wo, part);

    combine_kernel<<<(BB * NN * NN + 255) / 256, 256, 0, stream>>>(part, wob, out);
}

// Round 12
// 224.156 us; speedup vs baseline: 1.1033x; 1.1033x over previous
//
#include <hip/hip_runtime.h>
#include <hip/hip_bf16.h>

// Problem dims (fixed): B=4, N=256, D=512, L=3
#define BB 4
#define NN 256
#define DD 512

using short8   = __attribute__((ext_vector_type(8))) short;
using f32x4    = __attribute__((ext_vector_type(4))) float;
using uint32x4 = __attribute__((ext_vector_type(4))) unsigned int;

__device__ __forceinline__ unsigned short f2bf(float f) {
    unsigned int u = __float_as_uint(f);
    unsigned int r = (u + 0x7fffu + ((u >> 16) & 1u)) >> 16;
    return (unsigned short)r;
}

// packed f32->bf16 (RNE), 2 elems/instr
__device__ __forceinline__ unsigned cvtpk(float lo, float hi) {
    unsigned r;
    asm("v_cvt_pk_bf16_f32 %0, %1, %2" : "=v"(r) : "v"(lo), "v"(hi));
    return r;
}

// ---- 64-col (128B-row) tile helpers: used by highway/ab kernels ----
template <int ROWS, int NW>
__device__ __forceinline__ void stage_rows(const unsigned short* src, int stride,
                                           short* dst, int tid) {
    int wave = tid >> 6, lane = tid & 63;
#pragma unroll
    for (int c = 0; c < ROWS / (8 * NW); ++c) {
        int rbase = (c * NW + wave) * 8;
        int row   = rbase + (lane >> 3);
        int slot  = (lane & 7) ^ (row & 7);
        const unsigned short* g = src + (size_t)row * stride + slot * 8;
        __builtin_amdgcn_global_load_lds(
            (const __attribute__((address_space(1))) void*)g,
            (__attribute__((address_space(3))) void*)(dst + rbase * 64),
            16, 0, 0);
    }
}

__device__ __forceinline__ short8 read_frag(const short* T, int rowBase, int k2) {
    int lane = threadIdx.x & 63;
    int row  = rowBase + (lane & 15);
    int slot = ((k2 * 4) + (lane >> 4)) ^ (row & 7);
    return *(const short8*)(T + row * 64 + slot * 8);
}

// ---- 32-col (64B-row) tile helpers: pair kernel (BK=32) ----
// slot swizzle: slot' = slot ^ ((row>>1)&3) -> 16 rows spread 2x over 8
// bank-groups (2-way = free, m136).
template <int ROWS, int NW>
__device__ __forceinline__ void stage_rows32(const unsigned short* src, int stride,
                                             short* dst, int tid) {
    int wave = tid >> 6, lane = tid & 63;
#pragma unroll
    for (int c = 0; c < ROWS / (16 * NW); ++c) {
        int rbase = (c * NW + wave) * 16;
        int row   = rbase + (lane >> 2);
        int slot  = (lane & 3) ^ ((row >> 1) & 3);
        const unsigned short* g = src + (size_t)row * stride + slot * 8;
        __builtin_amdgcn_global_load_lds(
            (const __attribute__((address_space(1))) void*)g,
            (__attribute__((address_space(3))) void*)(dst + rbase * 32),
            16, 0, 0);
    }
}

__device__ __forceinline__ short8 read_frag32(const short* T, int rowBase) {
    int lane = threadIdx.x & 63;
    int row  = rowBase + (lane & 15);
    int slot = (lane >> 4) ^ ((row >> 1) & 3);
    return *(const short8*)(T + row * 32 + slot * 8);
}

// ---------------- prep: fp32 -> bf16 weight conversion + h0 init ----------------
__global__ void prep_kernel(const float* __restrict__ x,
                            const float* __restrict__ gw, const float* __restrict__ tw,
                            const float* __restrict__ w0, const float* __restrict__ w1,
                            float* __restrict__ h0_f32, unsigned short* __restrict__ h0_bf,
                            unsigned short* __restrict__ wg_bf, unsigned short* __restrict__ wt_bf,
                            unsigned short* __restrict__ w0c_bf, unsigned short* __restrict__ w1_bf) {
    const int S_X = BB * NN * DD;
    const int S_W = 3 * DD * DD;
    const int S_W0 = 2 * DD * DD;
    int total = S_X + S_W + S_W + S_W0 + DD * DD;
    for (int idx = blockIdx.x * blockDim.x + threadIdx.x; idx < total;
         idx += gridDim.x * blockDim.x) {
        int t = idx;
        if (t < S_X) { float v = x[t]; h0_f32[t] = v; h0_bf[t] = f2bf(v); continue; }
        t -= S_X;
        if (t < S_W) { wg_bf[t] = f2bf(gw[t]); continue; }
        t -= S_W;
        if (t < S_W) { wt_bf[t] = f2bf(tw[t]); continue; }
        t -= S_W;
        if (t < S_W0) {
            int e = t >> 9, d = t & 511;
            float v = (e < DD) ? w0[e * (2 * DD) + d] : w0[(e - DD) * (2 * DD) + DD + d];
            w0c_bf[t] = f2bf(v); continue;
        }
        t -= S_W0;
        w1_bf[t] = f2bf(w1[t]);
    }
}

// ---------------- highway layer (64x64 tiles, 4 waves, 128 blocks) ----------------
__global__ __launch_bounds__(256) void highway_kernel(
        const float* __restrict__ h_in, const unsigned short* __restrict__ hbf_in,
        const unsigned short* __restrict__ wg_bf, const unsigned short* __restrict__ wt_bf,
        const float* __restrict__ gb, const float* __restrict__ tb,
        float* __restrict__ h_out, unsigned short* __restrict__ hbf_out) {
    __shared__ short ht[64 * 64];
    __shared__ short wgt[64 * 64];
    __shared__ short wtt[64 * 64];
    int tid = threadIdx.x, lane = tid & 63, wave = tid >> 6;
    int mt = blockIdx.x >> 3, et = blockIdx.x & 7;
    int m0 = mt * 64, e0 = et * 64;
    int wm = wave >> 1, we = wave & 1;
    f32x4 gacc[2][2] = {}, tacc[2][2] = {};
    for (int ks = 0; ks < 8; ++ks) {
        int d0 = ks * 64;
        __syncthreads();
        stage_rows<64, 4>(hbf_in + (size_t)m0 * DD + d0, DD, ht, tid);
        stage_rows<64, 4>(wg_bf + (size_t)e0 * DD + d0, DD, wgt, tid);
        stage_rows<64, 4>(wt_bf + (size_t)e0 * DD + d0, DD, wtt, tid);
        __syncthreads();
#pragma unroll
        for (int k2 = 0; k2 < 2; ++k2) {
            short8 af[2], bg[2], bt[2];
#pragma unroll
            for (int f = 0; f < 2; ++f) af[f] = read_frag(ht, wm * 32 + f * 16, k2);
#pragma unroll
            for (int f = 0; f < 2; ++f) bg[f] = read_frag(wgt, we * 32 + f * 16, k2);
#pragma unroll
            for (int f = 0; f < 2; ++f) bt[f] = read_frag(wtt, we * 32 + f * 16, k2);
#pragma unroll
            for (int fm = 0; fm < 2; ++fm)
#pragma unroll
                for (int fn = 0; fn < 2; ++fn) {
                    gacc[fm][fn] = __builtin_amdgcn_mfma_f32_16x16x32_bf16(af[fm], bg[fn], gacc[fm][fn], 0, 0, 0);
                    tacc[fm][fn] = __builtin_amdgcn_mfma_f32_16x16x32_bf16(af[fm], bt[fn], tacc[fm][fn], 0, 0, 0);
                }
        }
    }
#pragma unroll
    for (int fm = 0; fm < 2; ++fm)
#pragma unroll
        for (int fn = 0; fn < 2; ++fn) {
            int e = e0 + we * 32 + fn * 16 + (lane & 15);
            float gbe = gb[e], tbe = tb[e];
#pragma unroll
            for (int r = 0; r < 4; ++r) {
                int m = m0 + wm * 32 + fm * 16 + (lane >> 4) * 4 + r;
                float g = 1.f / (1.f + __expf(-(gacc[fm][fn][r] + gbe)));
                float tv = tacc[fm][fn][r] + tbe; tv = tv > 0.f ? tv : 0.f;
                float ho = h_in[(size_t)m * DD + e];
                float hn = g * tv + (1.f - g) * ho;
                h_out[(size_t)m * DD + e] = hn;
                hbf_out[(size_t)m * DD + e] = f2bf(hn);
            }
        }
}

// ---------------- a/b projection (64x128 tiles, 4 waves, 128 blocks) ------------
__global__ __launch_bounds__(256) void ab_kernel(
        const unsigned short* __restrict__ hbf, const unsigned short* __restrict__ w0c_bf,
        const float* __restrict__ lw0_b,
        float* __restrict__ a_out, float* __restrict__ b_out) {
    __shared__ short ht[64 * 64];
    __shared__ short wt_[128 * 64];
    int tid = threadIdx.x, lane = tid & 63, wave = tid >> 6;
    int mt = blockIdx.x >> 3, et = blockIdx.x & 7;
    int m0 = mt * 64, e0 = et * 128;
    int wm = wave >> 1, we = wave & 1;
    f32x4 acc[2][4] = {};
    for (int ks = 0; ks < 8; ++ks) {
        __syncthreads();
        stage_rows<64, 4>(hbf + (size_t)m0 * DD + ks * 64, DD, ht, tid);
        stage_rows<128, 4>(w0c_bf + (size_t)e0 * DD + ks * 64, DD, wt_, tid);
        __syncthreads();
#pragma unroll
        for (int k2 = 0; k2 < 2; ++k2) {
            short8 af[2], bf_[4];
#pragma unroll
            for (int f = 0; f < 2; ++f) af[f] = read_frag(ht, wm * 32 + f * 16, k2);
#pragma unroll
            for (int f = 0; f < 4; ++f) bf_[f] = read_frag(wt_, we * 64 + f * 16, k2);
#pragma unroll
            for (int fm = 0; fm < 2; ++fm)
#pragma unroll
                for (int fn = 0; fn < 4; ++fn)
                    acc[fm][fn] = __builtin_amdgcn_mfma_f32_16x16x32_bf16(af[fm], bf_[fn], acc[fm][fn], 0, 0, 0);
        }
    }
#pragma unroll
    for (int fm = 0; fm < 2; ++fm)
#pragma unroll
        for (int fn = 0; fn < 4; ++fn) {
            int e = e0 + we * 64 + fn * 16 + (lane & 15);
#pragma unroll
            for (int r = 0; r < 4; ++r) {
                int m = m0 + wm * 32 + fm * 16 + (lane >> 4) * 4 + r;
                float v = acc[fm][fn][r];
                if (e < DD) a_out[(size_t)m * DD + e] = v + lw0_b[e];
                else        b_out[(size_t)m * DD + (e - DD)] = v;
            }
        }
}

// ------- fused pairwise kernel (v12: BK=32, W1 ring-3, depth-2 counted vmcnt) ----
// 8 waves, wave = 128j x 64e, acc[8][4] = 128 AGPR. 16 K-steps of 32.
// W1 ring-3 [512e][32k] (3x32KB) + z dbuf [128j][32k] (2x8KB) = 112KB LDS.
// stage(k+2) issued at step k; end-of-step wait = vmcnt(4) -> ONE FULL STAGE
// ALWAYS IN FLIGHT, never drained to 0 in the loop (T4, m218's +38-73% lever).
// Consume safety (m201 pattern): per-wave vmcnt(4) BEFORE the joining barrier
// guarantees all waves' stage(k+1) landed when step k+1 reads ws[(k+1)%3].
// WAR: ws ring distance 3 steps; zs distance 2 steps; both barrier-protected.

#define AB_LOADS(K)                                                           \
    {                                                                         \
        const int dl_ = (K) * 32 + s4 * 8;                                    \
        alo = *(const f32x4*)(arow + dl_);                                    \
        ahi = *(const f32x4*)(arow + dl_ + 4);                                \
        const float* bp_ = brow + (size_t)rr * DD + dl_;                      \
        blo = *(const f32x4*)bp_;                                             \
        bhi = *(const f32x4*)(bp_ + 4);                                       \
    }

#define Z_MATH_WRITE(BUF)                                                     \
    {                                                                         \
        uint32x4 zw;                                                          \
        zw[0] = cvtpk(fmaxf(alo[0] + blo[0], 0.f), fmaxf(alo[1] + blo[1], 0.f)); \
        zw[1] = cvtpk(fmaxf(alo[2] + blo[2], 0.f), fmaxf(alo[3] + blo[3], 0.f)); \
        zw[2] = cvtpk(fmaxf(ahi[0] + bhi[0], 0.f), fmaxf(ahi[1] + bhi[1], 0.f)); \
        zw[3] = cvtpk(fmaxf(ahi[2] + bhi[2], 0.f), fmaxf(ahi[3] + bhi[3], 0.f)); \
        *(uint32x4*)((BUF) + rr * 32 + ((s4 ^ ((rr >> 1) & 3)) * 8)) = zw;    \
    }

__global__ __launch_bounds__(512, 2) void pair_kernel(
        const float* __restrict__ a_f32, const float* __restrict__ b_f32,
        const unsigned short* __restrict__ w1_bf,
        const float* __restrict__ lw1_b, const float* __restrict__ lwo_w,
        const float* __restrict__ lwo_b, float* __restrict__ out) {
    __shared__ short ws[3][512 * 32];    // 96KB W1 ring (3 x [512e][32k])
    __shared__ short zs[2][128 * 32];    // 16KB z dbuf; s_red alias after loop
    int tid = threadIdx.x, lane = tid & 63, wave = tid >> 6;
    int bid = blockIdx.x;
    // bijective XCD swizzle: each XCD's blocks cover a contiguous i-range
    int swz = (bid & 7) * 256 + (bid >> 3);
    int bb = swz >> 9, i = (swz >> 1) & 255, j0 = (swz & 1) * 128;
    const float* arow = a_f32 + (size_t)(bb * NN + i) * DD;
    const float* brow = b_f32 + (size_t)(bb * NN + j0) * DD;
    int s4 = tid & 3, rr = tid >> 2;     // z producer: 16B slot (8k), row (0..127)
    int we = wave;                        // e-slice owner: e in [we*64, we*64+64)

    f32x4 acc[8][4] = {};
    f32x4 alo, ahi, blo, bhi;

    // ---- prologue: establish loop invariant ----
    AB_LOADS(0)
    __builtin_amdgcn_sched_barrier(0);
    stage_rows32<512, 8>(w1_bf, DD, ws[0], tid);          // stage(0): 4 loads
    __builtin_amdgcn_sched_barrier(0);
    Z_MATH_WRITE(zs[0])                  // implicit vmcnt(4): ab(0) done, stage(0) flying
    asm volatile("s_waitcnt lgkmcnt(0)" ::: "memory");
    stage_rows32<512, 8>(w1_bf + 32, DD, ws[1], tid);     // stage(1): 4 loads
    __builtin_amdgcn_sched_barrier(0);
    asm volatile("s_waitcnt vmcnt(4)" ::: "memory");      // stage(0) landed; (1) flying
    __builtin_amdgcn_s_barrier();        // invariant: ws[0] landed, zs[0] visible

#pragma unroll
    for (int k = 0; k < 16; ++k) {
        const short* zc = zs[k & 1];
        const short* wc = ws[k % 3];

        // ---- issue phase: ab(k+1) first, then stage(k+2) (order pinned) ----
        if (k < 15) {
            AB_LOADS(k + 1)
            __builtin_amdgcn_sched_barrier(0);
            if (k < 14)
                stage_rows32<512, 8>(w1_bf + (size_t)(k + 2) * 32, DD,
                                     ws[(k + 2) % 3], tid);
            __builtin_amdgcn_sched_barrier(0);
        }

        // ---- MFMA phase: 12 ds_reads + 32 MFMA ----
        {
            short8 bfr[4], af[8];
#pragma unroll
            for (int f = 0; f < 4; ++f) bfr[f] = read_frag32(wc, we * 64 + f * 16);
#pragma unroll
            for (int f = 0; f < 8; ++f) af[f] = read_frag32(zc, f * 16);
            asm volatile("s_waitcnt lgkmcnt(0)" ::: "memory");
            __builtin_amdgcn_sched_barrier(0);
            __builtin_amdgcn_s_setprio(1);
#pragma unroll
            for (int fm = 0; fm < 8; ++fm)
#pragma unroll
                for (int fn = 0; fn < 4; ++fn)
                    acc[fm][fn] = __builtin_amdgcn_mfma_f32_16x16x32_bf16(
                        af[fm], bfr[fn], acc[fm][fn], 0, 0, 0);
            __builtin_amdgcn_s_setprio(0);
        }

        // ---- z(k+1) produce (implicit wait = vmcnt(4): ab done, stage(k+2) flying) ----
        if (k < 15) {
            Z_MATH_WRITE(zs[(k + 1) & 1])
            asm volatile("s_waitcnt lgkmcnt(0)" ::: "memory");
            // own stage(k+1) landed; stage(k+2) stays in flight across barrier
            if (k < 14) asm volatile("s_waitcnt vmcnt(4)" ::: "memory");
            else        asm volatile("s_waitcnt vmcnt(0)" ::: "memory");
            __builtin_amdgcn_s_barrier();   // all waves: ws[(k+1)%3] + zs[(k+1)&1] ready
        }
    }

    // ---- epilogue: relu(acc+b1)*wo, reduce over all e ----
    __syncthreads();                     // all zs reads done -> alias as s_red
    float* s_red = (float*)zs;           // 8 waves x 128 j partials (4KB)
#pragma unroll
    for (int fm = 0; fm < 8; ++fm) {
        float red[4] = {0.f, 0.f, 0.f, 0.f};
#pragma unroll
        for (int fn = 0; fn < 4; ++fn) {
            int e = we * 64 + fn * 16 + (lane & 15);
            float b1e = lw1_b[e], woe = lwo_w[e];
#pragma unroll
            for (int r = 0; r < 4; ++r) {
                float v = acc[fm][fn][r] + b1e;
                red[r] += (v > 0.f) ? v * woe : 0.f;
            }
        }
#pragma unroll
        for (int mask = 1; mask < 16; mask <<= 1)
#pragma unroll
            for (int r = 0; r < 4; ++r) red[r] += __shfl_xor(red[r], mask, 64);
        if ((lane & 15) == 0) {
#pragma unroll
            for (int r = 0; r < 4; ++r)
                s_red[we * 128 + fm * 16 + (lane >> 4) * 4 + r] = red[r];
        }
    }
    __syncthreads();
    if (tid < 128) {
        float v = lwo_b[0];
#pragma unroll
        for (int w8 = 0; w8 < 8; ++w8) v += s_red[w8 * 128 + tid];
        out[((size_t)(bb * NN + i)) * NN + j0 + tid] = 1.f / (1.f + __expf(-v));
    }
}

extern "C" void kernel_launch(void* const* d_in, const int* in_sizes, int n_in,
                              void* d_out, int out_size, void* d_ws, size_t ws_size,
                              hipStream_t stream) {
    const float* x    = (const float*)d_in[0];
    const float* gw   = (const float*)d_in[1];
    const float* gb   = (const float*)d_in[2];
    const float* tw   = (const float*)d_in[3];
    const float* tb   = (const float*)d_in[4];
    const float* w0   = (const float*)d_in[5];
    const float* w0b  = (const float*)d_in[6];
    const float* w1   = (const float*)d_in[7];
    const float* w1b_ = (const float*)d_in[8];
    const float* wo   = (const float*)d_in[9];
    const float* wob  = (const float*)d_in[10];
    float* out = (float*)d_out;

    char* w = (char*)d_ws;
    float* hA  = (float*)w;            w += (size_t)BB * NN * DD * 4;
    float* hB  = (float*)w;            w += (size_t)BB * NN * DD * 4;
    unsigned short* hbA = (unsigned short*)w; w += (size_t)BB * NN * DD * 2;
    unsigned short* hbB = (unsigned short*)w; w += (size_t)BB * NN * DD * 2;
    float* a_f = (float*)w;            w += (size_t)BB * NN * DD * 4;
    float* b_f = (float*)w;            w += (size_t)BB * NN * DD * 4;
    unsigned short* wg_bf  = (unsigned short*)w; w += (size_t)3 * DD * DD * 2;
    unsigned short* wt_bf  = (unsigned short*)w; w += (size_t)3 * DD * DD * 2;
    unsigned short* w0c_bf = (unsigned short*)w; w += (size_t)2 * DD * DD * 2;
    unsigned short* w1_bf  = (unsigned short*)w; w += (size_t)DD * DD * 2;

    prep_kernel<<<1024, 256, 0, stream>>>(x, gw, tw, w0, w1, hA, hbA, wg_bf, wt_bf, w0c_bf, w1_bf);

    highway_kernel<<<128, 256, 0, stream>>>(hA, hbA, wg_bf + 0 * DD * DD, wt_bf + 0 * DD * DD,
                                            gb + 0 * DD, tb + 0 * DD, hB, hbB);
    highway_kernel<<<128, 256, 0, stream>>>(hB, hbB, wg_bf + 1 * DD * DD, wt_bf + 1 * DD * DD,
                                            gb + 1 * DD, tb + 1 * DD, hA, hbA);
    highway_kernel<<<128, 256, 0, stream>>>(hA, hbA, wg_bf + 2 * DD * DD, wt_bf + 2 * DD * DD,
                                            gb + 2 * DD, tb + 2 * DD, hB, hbB);

    ab_kernel<<<128, 256, 0, stream>>>(hbB, w0c_bf, w0b, a_f, b_f);

    pair_kernel<<<2048, 512, 0, stream>>>(a_f, b_f, w1_bf, w1b_, wo, wob, out);
}